// Round 16
// baseline (401.789 us; speedup 1.0000x reference)
//
#include <hip/hip_runtime.h>
#include <hip/hip_bf16.h>
#include <math.h>

// Problem constants (from reference)
constexpr int NTOT = 4608;   // N_NODES
constexpr int TC   = 3072;   // TOTAL_CATS
constexpr int MU   = 1536;   // MAX_UNIFY
constexpr int NH   = 4;      // heads

// ---------------- workspace layout (float offsets) ----------------
constexpr long OFF_ADJ  = 0;                                  // N*N sim region (partially used)
constexpr long OFF_X1   = OFF_ADJ  + (long)NTOT*NTOT;         // N*256 (pre-relu)
constexpr long OFF_NAF  = OFF_X1   + (long)NTOT*256;          // naf_T [64][NTOT]
constexpr long OFF_PART = OFF_NAF  + (long)NTOT*64;           // (unused)
constexpr long OFF_RINV = OFF_PART + 72*64;                   // N
constexpr long OFF_WH   = OFF_RINV + NTOT;                    // 4*N*64  (later: mask bitfield)
constexpr long OFF_F1H  = OFF_WH   + (long)4*NTOT*64;         // 4*N
constexpr long OFF_F2H  = OFF_F1H  + (long)4*NTOT;
constexpr long OFF_MXH  = OFF_F2H  + (long)4*NTOT;            // (unused)
constexpr long OFF_CIH  = OFF_MXH  + (long)4*NTOT;            // (unused)
constexpr long OFF_X2   = OFF_CIH  + (long)4*NTOT;            // N*256
constexpr long OFF_WH2  = OFF_X2   + (long)NTOT*256;          // N*256 (acc1 before Wh2 exists)
constexpr long OFF_F1S  = OFF_WH2  + (long)NTOT*256;          // N
constexpr long OFF_F2S  = OFF_F1S  + NTOT;
constexpr long OFF_MXS  = OFF_F2S  + NTOT;                    // (unused)
constexpr long OFF_CIS  = OFF_MXS  + NTOT;                    // (unused)
constexpr long OFF_X3   = OFF_CIS  + NTOT;                    // 1536*256
constexpr long OFF_PMAX = OFF_X3   + (long)MU*256;            // 2*12*1536
constexpr long OFF_PSUM = OFF_PMAX + (long)2*12*MU;
constexpr long OFF_FMAX = OFF_PSUM + (long)2*12*MU;           // 2*1536
constexpr long OFF_FIS  = OFF_FMAX + (long)2*MU;
constexpr long OFF_L1   = OFF_FIS  + (long)2*MU;              // 4*N unnormalized row sums (mh)
constexpr long OFF_L2   = OFF_L1   + (long)4*NTOT;            // MU row sums (s)
// sim region: values stored ONLY for rows<TC, cols>=TC. Rows>=TC carved as scratch:
constexpr long OFF_PARTS = OFF_ADJ + (long)TC*NTOT;           // double[NTOT][36] row-sum partials
constexpr long OFF_POSB  = OFF_PARTS + 2L*NTOT*72;            // u64[NTOT][72] sign words
// Aliases (lifetime-checked):
//   acc1  = OFF_WH2 region (dead until Wh2 gemm, after mh_fin)
//   Whbf  = OFF_X2 region as bf16 (x2 written only by mh_fin)
//   maskb = OFF_WH region as u64[NTOT][72] (Wh fp32 dead after cvt_t+dots_k)
//   acc2  = OFF_X1 (x1p dead after mh_fin); Wh2bf = OFF_X1 + MU*256 as bf16

typedef __attribute__((ext_vector_type(8))) short bf16x8;
typedef __attribute__((ext_vector_type(8))) unsigned short ushort8;
typedef __attribute__((ext_vector_type(4))) float floatx4;

__device__ __forceinline__ float lrelu(float x) { return (x >= 0.f) ? x : 0.2f * x; }
__device__ __forceinline__ float elu(float x)   { return (x > 0.f) ? x : expm1f(x); }
__device__ __forceinline__ unsigned short f2bf(float f) {
    unsigned u = __float_as_uint(f);
    u += 0x7FFFu + ((u >> 16) & 1u);           // round-to-nearest-even
    return (unsigned short)(u >> 16);
}

// ---------------- zero-fill (float4) ----------------
__global__ __launch_bounds__(256) void zero_k(float* __restrict__ p)
{
    long idx = ((long)blockIdx.x * 256 + threadIdx.x) * 4;
    *(float4*)(p + idx) = make_float4(0.f, 0.f, 0.f, 0.f);
}

// ---------------- convert + transpose: in [Z][NTOT][D] fp32 -> out [Z][D][NTOT] bf16 ----------------
__global__ __launch_bounds__(256) void cvt_t(
    const float* __restrict__ in, unsigned short* __restrict__ out,
    int D, long inZ, long outZ)
{
    __shared__ float t[64][65];
    int n0 = blockIdx.x * 64, d0 = blockIdx.y * 64;
    const float* inz = in + (long)blockIdx.z * inZ;
    unsigned short* outz = out + (long)blockIdx.z * outZ;
    int tid = threadIdx.x;
    int r4 = tid >> 6, k = tid & 63;
    #pragma unroll
    for (int l = 0; l < 16; ++l) {
        int row = l * 4 + r4;
        t[row][k] = inz[(long)(n0 + row) * D + d0 + k];
    }
    __syncthreads();
    #pragma unroll
    for (int l = 0; l < 16; ++l) {
        int drow = l * 4 + r4;
        outz[(long)(d0 + drow) * NTOT + n0 + k] = f2bf(t[k][drow]);
    }
}

// ---------------- generic tiled fp32 GEMM: C = A(NxK) @ B(KxM) [+bias] ----------------
template<bool RELU_A, bool BIAS>
__global__ __launch_bounds__(256) void gemm_rm(
    const float* __restrict__ A, const float* __restrict__ B,
    const float* __restrict__ bias, float* __restrict__ C,
    int K, int M, long strideBz, long strideCz)
{
    __shared__ float As[16][68];
    __shared__ float Bs[16][68];
    const float* Bz = B + (long)blockIdx.z * strideBz;
    float* Cz = C + (long)blockIdx.z * strideCz;
    int tid = threadIdx.x;
    int r0 = blockIdx.x * 64;
    int c0 = blockIdx.y * 64;
    int ty = tid >> 4, tx = tid & 15;
    int srow = tid >> 2, skg = tid & 3;     // As staging role
    float acc[4][4] = {};
    for (int k0 = 0; k0 < K; k0 += 16) {
        {
            float4 v = *(const float4*)&A[(long)(r0 + srow) * K + k0 + skg * 4];
            if (RELU_A) {
                v.x = fmaxf(v.x, 0.f); v.y = fmaxf(v.y, 0.f);
                v.z = fmaxf(v.z, 0.f); v.w = fmaxf(v.w, 0.f);
            }
            As[skg * 4 + 0][srow] = v.x;
            As[skg * 4 + 1][srow] = v.y;
            As[skg * 4 + 2][srow] = v.z;
            As[skg * 4 + 3][srow] = v.w;
        }
        #pragma unroll
        for (int l = 0; l < 4; ++l) {
            int idx = l * 256 + tid;
            int kk = idx >> 6, col = idx & 63;
            Bs[kk][col] = Bz[(long)(k0 + kk) * M + c0 + col];
        }
        __syncthreads();
        #pragma unroll
        for (int kk = 0; kk < 16; ++kk) {
            float4 av = *(const float4*)&As[kk][ty * 4];
            float4 bv = *(const float4*)&Bs[kk][tx * 4];
            float a[4] = { av.x, av.y, av.z, av.w };
            float b[4] = { bv.x, bv.y, bv.z, bv.w };
            #pragma unroll
            for (int i = 0; i < 4; ++i)
                #pragma unroll
                for (int j = 0; j < 4; ++j) acc[i][j] += a[i] * b[j];
        }
        __syncthreads();
    }
    #pragma unroll
    for (int i = 0; i < 4; ++i) {
        int r = r0 + ty * 4 + i;
        #pragma unroll
        for (int j = 0; j < 4; ++j) {
            int c = c0 + tx * 4 + j;
            float v = acc[i][j];
            if (BIAS) v += bias[c];
            Cz[(long)r * M + c] = v;
        }
    }
}

// ---------------- af = x1 @ W_adj + b_adj; naf_T[k][n] = af/||af|| (transposed) ----------------
__global__ __launch_bounds__(256) void af_naf(
    const float* __restrict__ x1, const float* __restrict__ W_adj,
    const float* __restrict__ b_adj, float* __restrict__ nafT)
{
    __shared__ float rowbuf[4][256];
    int tid = threadIdx.x, w = tid >> 6, lane = tid & 63;
    int n = blockIdx.x * 4 + w;
    #pragma unroll
    for (int l = 0; l < 4; ++l) rowbuf[w][l * 64 + lane] = x1[(long)n * 256 + l * 64 + lane];
    __syncthreads();
    float acc = b_adj[lane];
    for (int k = 0; k < 256; ++k) acc += rowbuf[w][k] * W_adj[k * 64 + lane];
    float sq = acc * acc;
    #pragma unroll
    for (int off = 32; off >= 1; off >>= 1) sq += __shfl_xor(sq, off);
    float nrm = fmaxf(sqrtf(sq), 1e-12f);
    nafT[(long)lane * NTOT + n] = acc / nrm;
}

// ---------------- sim 128x128 tile, k-chunked LDS (16 k's), fused partials + signs ----------------
// grid (36, 36). Values stored only for n<TC, m>=TC. Bs skewed (+4 per 32 cols).
// kk order sequential 0..63 -> sim values bit-identical to 64-tile version.
__global__ __launch_bounds__(256) void sim_k(
    const float* __restrict__ nafT, float* __restrict__ sim,
    double* __restrict__ parts, unsigned long long* __restrict__ posb)
{
    __shared__ float As[16][132];          // [k][row], unskewed (reads are 4-addr broadcast)
    __shared__ float Bs[16][140];          // [k][col skewed]
    __shared__ unsigned char sgn[128][16];
    int tid = threadIdx.x;
    int n0 = blockIdx.x * 128, m0 = blockIdx.y * 128;
    int ty = tid >> 4, tx = tid & 15;
    int cp = tx * 8 + ((tx >> 2) << 2);    // skewed col base (2-way banks)
    float acc[8][8] = {};
    for (int kc = 0; kc < 64; kc += 16) {
        __syncthreads();                   // previous chunk's reads complete
        #pragma unroll
        for (int l = 0; l < 8; ++l) {
            int flat = l * 256 + tid;
            int k = flat >> 7, c = flat & 127;    // lane = col: coalesced + 2-way LDS writes
            As[k][c] = nafT[(long)(kc + k) * NTOT + n0 + c];
            Bs[k][c + ((c >> 5) << 2)] = nafT[(long)(kc + k) * NTOT + m0 + c];
        }
        __syncthreads();
        #pragma unroll
        for (int kk = 0; kk < 16; ++kk) {
            float4 a0 = *(const float4*)&As[kk][ty * 8];
            float4 a1 = *(const float4*)&As[kk][ty * 8 + 4];
            float4 b0 = *(const float4*)&Bs[kk][cp];
            float4 b1 = *(const float4*)&Bs[kk][cp + 4];
            float a[8] = { a0.x, a0.y, a0.z, a0.w, a1.x, a1.y, a1.z, a1.w };
            float b[8] = { b0.x, b0.y, b0.z, b0.w, b1.x, b1.y, b1.z, b1.w };
            #pragma unroll
            for (int i = 0; i < 8; ++i)
                #pragma unroll
                for (int j = 0; j < 8; ++j) acc[i][j] += a[i] * b[j];
        }
    }
    // values only for bi-softmax slice
    if (m0 >= TC && n0 < TC) {
        #pragma unroll
        for (int i = 0; i < 8; ++i) {
            long r = n0 + ty * 8 + i;
            float4 o0 = make_float4(acc[i][0], acc[i][1], acc[i][2], acc[i][3]);
            float4 o1 = make_float4(acc[i][4], acc[i][5], acc[i][6], acc[i][7]);
            *(float4*)(sim + r * NTOT + m0 + tx * 8) = o0;
            *(float4*)(sim + r * NTOT + m0 + tx * 8 + 4) = o1;
        }
    }
    // fused per-row fp64 partials (stride 36) + sign bytes
    #pragma unroll
    for (int i = 0; i < 8; ++i) {
        double t = ((double)acc[i][0] + (double)acc[i][1]) + ((double)acc[i][2] + (double)acc[i][3])
                 + ((double)acc[i][4] + (double)acc[i][5]) + ((double)acc[i][6] + (double)acc[i][7]);
        #pragma unroll
        for (int off = 1; off < 16; off <<= 1) t += __shfl_xor(t, off);
        unsigned byte = 0;
        #pragma unroll
        for (int j = 0; j < 8; ++j) byte |= (unsigned)(acc[i][j] > 0.f) << j;
        sgn[ty * 8 + i][tx] = (unsigned char)byte;
        if (tx == 0) parts[(long)(n0 + ty * 8 + i) * 36 + blockIdx.y] = t;
    }
    __syncthreads();
    if (tid < 128) {
        unsigned long long w0 = 0, w1 = 0;
        #pragma unroll
        for (int t = 0; t < 8; ++t) {
            w0 |= (unsigned long long)sgn[tid][t] << (8 * t);
            w1 |= (unsigned long long)sgn[tid][8 + t] << (8 * t);
        }
        posb[(long)(n0 + tid) * 72 + 2 * blockIdx.y] = w0;
        posb[(long)(n0 + tid) * 72 + 2 * blockIdx.y + 1] = w1;
    }
}

// ---------------- rowfin: combine 36 partials -> rinv; sign words -> mask words ----------------
__global__ __launch_bounds__(256) void rowfin(
    const double* __restrict__ parts, const unsigned long long* __restrict__ posb,
    float* __restrict__ rinv, unsigned long long* __restrict__ maskb)
{
    int tid = threadIdx.x, w = tid >> 6, lane = tid & 63;
    int n = blockIdx.x * 4 + w;
    double s = (lane < 36) ? parts[(long)n * 36 + lane] : 0.0;
    #pragma unroll
    for (int off = 32; off >= 1; off >>= 1) s += __shfl_xor(s, off);
    float rs = (float)s;
    float r = 1.0f / rs;
    if (isinf(r)) r = 0.f;
    if (lane == 0) rinv[n] = r;
    unsigned long long pw = posb[(long)n * 72 + lane];
    unsigned long long mw = (r < 0.f) ? ~pw : pw;
    if (r == 0.f) mw = 0ull;
    maskb[(long)n * 72 + lane] = mw;
    if (lane < 8) {
        pw = posb[(long)n * 72 + 64 + lane];
        mw = (r < 0.f) ? ~pw : pw;
        if (r == 0.f) mw = 0ull;
        maskb[(long)n * 72 + 64 + lane] = mw;
    }
}

// ---------------- f1/f2 dots ----------------
__global__ __launch_bounds__(256) void dots_k(
    const float* __restrict__ Wh, const float* __restrict__ a,
    float* __restrict__ f1, float* __restrict__ f2, int D)
{
    int tid = threadIdx.x, w = tid >> 6, lane = tid & 63;
    int n = blockIdx.x * 4 + w;
    int h = blockIdx.y;
    const float* row = Wh + ((long)h * NTOT + n) * D;
    const float* a1 = a + (long)h * 2 * D;
    const float* a2 = a1 + D;
    float p1 = 0.f, p2 = 0.f;
    for (int d = lane; d < D; d += 64) {
        float v = row[d];
        p1 += v * a1[d];
        p2 += v * a2[d];
    }
    #pragma unroll
    for (int off = 32; off >= 1; off >>= 1) { p1 += __shfl_xor(p1, off); p2 += __shfl_xor(p2, off); }
    if (lane == 0) { f1[(long)h * NTOT + n] = p1; f2[(long)h * NTOT + n] = p2; }
}

// ---------------- multihead att @ Wh via bf16 MFMA, mask-bit P, in-register A-frags ----------------
__global__ __launch_bounds__(256) void mh_attn(
    const unsigned long long* __restrict__ maskb,
    const float* __restrict__ f1, const float* __restrict__ f2,
    const unsigned short* __restrict__ Whbf, float* __restrict__ accb,
    float* __restrict__ lbuf)
{
    __shared__ unsigned short Ws[2][64][72];   // Wh tile transposed [d][m] bf16
    int tid = threadIdx.x;
    int wave = tid >> 6, lane = tid & 63;
    int n0 = blockIdx.x * 64;
    int h = blockIdx.y, ch = blockIdx.z;
    const float* f2h = f2 + (long)h * NTOT;
    const unsigned short* Wb = Whbf + (long)h * 64 * NTOT;
    int wd = tid >> 2, wc = (tid & 3) * 16;
    int arow = lane & 15, acol8 = (lane >> 4) * 8;
    int n = n0 + 16 * wave + arow;
    float r1 = f1[(long)h * NTOT + n];
    float lsum = 0.f;
    floatx4 acc[4] = {};
    int buf = 0;
    for (int mt = ch * 12; mt < ch * 12 + 12; ++mt) {
        int m0 = mt * 64;
        ushort8 wv0 = *(const ushort8*)&Wb[(long)wd * NTOT + m0 + wc];
        ushort8 wv1 = *(const ushort8*)&Wb[(long)wd * NTOT + m0 + wc + 8];
        unsigned long long mw = maskb[(long)n * 72 + mt];
        bf16x8 afr[2];
        #pragma unroll
        for (int ks = 0; ks < 2; ++ks) {
            int mc = m0 + ks * 32 + acol8;
            float4 fv0 = *(const float4*)(f2h + mc);
            float4 fv1 = *(const float4*)(f2h + mc + 4);
            unsigned bits = (unsigned)(mw >> (ks * 32 + acol8)) & 0xFFu;
            float f[8] = { fv0.x, fv0.y, fv0.z, fv0.w, fv1.x, fv1.y, fv1.z, fv1.w };
            #pragma unroll
            for (int j = 0; j < 8; ++j) {
                float s = r1 + f[j];
                float e = __expf(fmaxf(s, 0.2f * s));
                float p = ((bits >> j) & 1u) ? e : 0.f;
                lsum += p;
                afr[ks][j] = (short)f2bf(p);
            }
        }
        *(ushort8*)&Ws[buf][wd][wc] = wv0;
        *(ushort8*)&Ws[buf][wd][wc + 8] = wv1;
        __syncthreads();
        #pragma unroll
        for (int ks = 0; ks < 2; ++ks) {
            #pragma unroll
            for (int dt = 0; dt < 4; ++dt) {
                bf16x8 bfr = *(bf16x8*)&Ws[buf][16 * dt + arow][ks * 32 + acol8];
                acc[dt] = __builtin_amdgcn_mfma_f32_16x16x32_bf16(afr[ks], bfr, acc[dt], 0, 0, 0);
            }
        }
        buf ^= 1;
    }
    lsum += __shfl_xor(lsum, 16);
    lsum += __shfl_xor(lsum, 32);
    if (lane < 16) atomicAdd(lbuf + (long)h * NTOT + n0 + 16 * wave + lane, lsum);
    int crow = n0 + 16 * wave + (lane >> 4) * 4;
    int ccol = h * 64 + (lane & 15);
    #pragma unroll
    for (int dt = 0; dt < 4; ++dt)
        #pragma unroll
        for (int r = 0; r < 4; ++r)
            atomicAdd(accb + (long)(crow + r) * 256 + ccol + dt * 16, acc[dt][r]);
}

// ---------------- mh epilogue: x2 = elu(acc / l') + relu(x1) ----------------
__global__ __launch_bounds__(256) void mh_fin(
    const float* __restrict__ accb, const float* __restrict__ lbuf,
    const float* __restrict__ x1, float* __restrict__ x2)
{
    long idx = ((long)blockIdx.x * 256 + threadIdx.x) * 4;
    long r = idx >> 8;
    int h = (int)((idx & 255) >> 6);
    float l = lbuf[(long)h * NTOT + r];
    float inv = (l > 0.f) ? 1.0f / l : 0.f;
    float4 a = *(const float4*)(accb + idx);
    float4 xv = *(const float4*)(x1 + idx);
    float4 o;
    o.x = elu(a.x * inv) + fmaxf(xv.x, 0.f);
    o.y = elu(a.y * inv) + fmaxf(xv.y, 0.f);
    o.z = elu(a.z * inv) + fmaxf(xv.z, 0.f);
    o.w = elu(a.w * inv) + fmaxf(xv.w, 0.f);
    *(float4*)(x2 + idx) = o;
}

// ---------------- single-head att @ Wh2 via bf16 MFMA (rows >= TC), mask-bit P ----------------
__global__ __launch_bounds__(256) void s_attn(
    const unsigned long long* __restrict__ maskb,
    const float* __restrict__ f1, const float* __restrict__ f2,
    const unsigned short* __restrict__ Wh2bf, float* __restrict__ accb,
    float* __restrict__ lbuf)
{
    __shared__ unsigned short Ws[2][64][72];
    int tid = threadIdx.x;
    int wave = tid >> 6, lane = tid & 63;
    int lr0 = blockIdx.x * 32;
    int c0 = blockIdx.y * 64;
    int ch = blockIdx.z;
    int wd = tid >> 2, wc = (tid & 3) * 16;
    int arow = lane & 15, acol8 = (lane >> 4) * 8;
    int rt = wave & 1;
    int dt0 = (wave >> 1) * 2;
    int n = TC + lr0 + 16 * rt + arow;
    float r1 = f1[n];
    float lsum = 0.f;
    floatx4 acc[2] = {};
    int buf = 0;
    for (int mt = ch * 12; mt < ch * 12 + 12; ++mt) {
        int m0 = mt * 64;
        ushort8 wv0 = *(const ushort8*)&Wh2bf[(long)(c0 + wd) * NTOT + m0 + wc];
        ushort8 wv1 = *(const ushort8*)&Wh2bf[(long)(c0 + wd) * NTOT + m0 + wc + 8];
        unsigned long long mw = maskb[(long)n * 72 + mt];
        bf16x8 afr[2];
        #pragma unroll
        for (int ks = 0; ks < 2; ++ks) {
            int mc = m0 + ks * 32 + acol8;
            float4 fv0 = *(const float4*)(f2 + mc);
            float4 fv1 = *(const float4*)(f2 + mc + 4);
            unsigned bits = (unsigned)(mw >> (ks * 32 + acol8)) & 0xFFu;
            float f[8] = { fv0.x, fv0.y, fv0.z, fv0.w, fv1.x, fv1.y, fv1.z, fv1.w };
            #pragma unroll
            for (int j = 0; j < 8; ++j) {
                float s = r1 + f[j];
                float e = __expf(fmaxf(s, 0.2f * s));
                float p = ((bits >> j) & 1u) ? e : 0.f;
                lsum += p;
                afr[ks][j] = (short)f2bf(p);
            }
        }
        *(ushort8*)&Ws[buf][wd][wc] = wv0;
        *(ushort8*)&Ws[buf][wd][wc + 8] = wv1;
        __syncthreads();
        #pragma unroll
        for (int ks = 0; ks < 2; ++ks) {
            #pragma unroll
            for (int t = 0; t < 2; ++t) {
                bf16x8 bfr = *(bf16x8*)&Ws[buf][16 * (dt0 + t) + arow][ks * 32 + acol8];
                acc[t] = __builtin_amdgcn_mfma_f32_16x16x32_bf16(afr[ks], bfr, acc[t], 0, 0, 0);
            }
        }
        buf ^= 1;
    }
    lsum += __shfl_xor(lsum, 16);
    lsum += __shfl_xor(lsum, 32);
    if (blockIdx.y == 0 && wave < 2 && lane < 16)
        atomicAdd(lbuf + lr0 + 16 * wave + lane, lsum);
    int crow = lr0 + 16 * rt + (lane >> 4) * 4;
    int ccol = c0 + (lane & 15);
    #pragma unroll
    for (int t = 0; t < 2; ++t)
        #pragma unroll
        for (int r = 0; r < 4; ++r)
            atomicAdd(accb + (long)(crow + r) * 256 + ccol + (dt0 + t) * 16, acc[t][r]);
}

// ---------------- s epilogue: x3 = elu(acc / l' + x2[TC..]) ----------------
__global__ __launch_bounds__(256) void s_fin(
    const float* __restrict__ accb, const float* __restrict__ lbuf,
    const float* __restrict__ x2, float* __restrict__ x3)
{
    long idx = ((long)blockIdx.x * 256 + threadIdx.x) * 4;
    long r = idx >> 8;
    float l = lbuf[r];
    float inv = (l > 0.f) ? 1.0f / l : 0.f;
    float4 a = *(const float4*)(accb + idx);
    float4 xv = *(const float4*)(x2 + (long)TC * 256 + idx);
    float4 o;
    o.x = elu(a.x * inv + xv.x);
    o.y = elu(a.y * inv + xv.y);
    o.z = elu(a.z * inv + xv.z);
    o.w = elu(a.w * inv + xv.w);
    *(float4*)(x3 + idx) = o;
}

// ---------------- bi-softmax phase A ----------------
__global__ __launch_bounds__(256) void bi_partial(
    const float* __restrict__ sim, const float* __restrict__ rinv,
    float* __restrict__ pmax, float* __restrict__ psum)
{
    int c = blockIdx.x * 256 + threadIdx.x;
    int ch = blockIdx.y;
    int ds = blockIdx.z;
    float m = -3.0e38f, s = 0.f;
    int rbase = ds * MU + ch * 128;
    for (int r = 0; r < 128; ++r) {
        float a = sim[(long)(rbase + r) * NTOT + TC + c] * rinv[rbase + r];
        float v = a * 20.0f;
        if (v <= m) s += expf(v - m);
        else { s = s * expf(m - v) + 1.f; m = v; }
    }
    pmax[((long)ds * 12 + ch) * MU + c] = m;
    psum[((long)ds * 12 + ch) * MU + c] = s;
}

// ---------------- bi-softmax phase B ----------------
__global__ __launch_bounds__(256) void bi_combine(
    const float* __restrict__ pmax, const float* __restrict__ psum,
    float* __restrict__ fmax, float* __restrict__ fis)
{
    int b = blockIdx.x;
    int ds = b / 6, ct = b % 6;
    int c = ct * 256 + threadIdx.x;
    float m = -3.0e38f;
    for (int ch = 0; ch < 12; ++ch) m = fmaxf(m, pmax[((long)ds * 12 + ch) * MU + c]);
    float s = 0.f;
    for (int ch = 0; ch < 12; ++ch)
        s += psum[((long)ds * 12 + ch) * MU + c] * expf(pmax[((long)ds * 12 + ch) * MU + c] - m);
    fmax[ds * MU + c] = m;
    fis[ds * MU + c] = 1.0f / s;
}

// ---------------- bi-softmax phase C ----------------
__global__ __launch_bounds__(256) void bi_norm(
    const float* __restrict__ sim, const float* __restrict__ rinv,
    const float* __restrict__ fmax, const float* __restrict__ fis,
    float* __restrict__ outbg)
{
    int c = blockIdx.x * 256 + threadIdx.x;
    int ch = blockIdx.y;
    int ds = blockIdx.z;
    float m = fmax[ds * MU + c], inv = fis[ds * MU + c];
    long obase = (long)ds * MU * MU;
    int rbase = ch * 128;
    for (int r = 0; r < 128; ++r) {
        int row = ds * MU + rbase + r;
        float a = sim[(long)row * NTOT + TC + c] * rinv[row];
        float v = a * 20.0f;
        outbg[obase + (long)(rbase + r) * MU + c] = expf(v - m) * inv;
    }
}

// ---------------- launch ----------------
extern "C" void kernel_launch(void* const* d_in, const int* in_sizes, int n_in,
                              void* d_out, int out_size, void* d_ws, size_t ws_size,
                              hipStream_t stream)
{
    const float* x        = (const float*)d_in[0];
    const float* W_before = (const float*)d_in[1];
    const float* b_before = (const float*)d_in[2];
    const float* W_adj    = (const float*)d_in[3];
    const float* b_adj    = (const float*)d_in[4];
    const float* W_heads  = (const float*)d_in[5];
    const float* a_heads  = (const float*)d_in[6];
    const float* W_out    = (const float*)d_in[7];
    const float* a_out    = (const float*)d_in[8];
    const float* W_lin1   = (const float*)d_in[9];
    const float* b_lin1   = (const float*)d_in[10];
    float* out = (float*)d_out;
    float* ws  = (float*)d_ws;

    float* sim  = ws + OFF_ADJ;
    float* x1p  = ws + OFF_X1;
    float* nafT = ws + OFF_NAF;
    float* rinv = ws + OFF_RINV;
    float* Wh   = ws + OFF_WH;
    float* f1h  = ws + OFF_F1H;
    float* f2h  = ws + OFF_F2H;
    float* x2   = ws + OFF_X2;
    float* Wh2  = ws + OFF_WH2;
    float* f1s  = ws + OFF_F1S;
    float* f2s  = ws + OFF_F2S;
    float* x3   = ws + OFF_X3;
    float* pmax = ws + OFF_PMAX;
    float* psum = ws + OFF_PSUM;
    float* fmx  = ws + OFF_FMAX;
    float* fis  = ws + OFF_FIS;
    float* l1   = ws + OFF_L1;
    float* l2   = ws + OFF_L2;
    float* acc1 = ws + OFF_WH2;                               // alias (see layout notes)
    float* acc2 = ws + OFF_X1;                                // alias
    unsigned short* Whbf  = (unsigned short*)(ws + OFF_X2);   // alias: x2 region before mh_fin
    unsigned short* Wh2bf = (unsigned short*)(ws + OFF_X1 + (long)MU * 256);  // alias
    unsigned long long* maskb = (unsigned long long*)(ws + OFF_WH);  // alias: Wh fp32 dead after dots_k
    double* parts = (double*)(ws + OFF_PARTS);                // in dead sim rows >= TC
    unsigned long long* posb = (unsigned long long*)(ws + OFF_POSB);

    dim3 b256(256);

    // zero mh partial accumulator (aliases Wh2 region) and l1+l2 row-sum buffers
    zero_k<<<dim3(NTOT * 256 / 1024), b256, 0, stream>>>(acc1);
    zero_k<<<dim3(20), b256, 0, stream>>>(l1);   // covers l1 (4*N) + l2 (MU) + pad
    // x1_pre = x @ W_before + b
    gemm_rm<false, true><<<dim3(72, 4, 1), b256, 0, stream>>>(x, W_before, b_before, x1p, 512, 256, 0, 0);
    // adjacency features: transposed naf, 128-tile k-chunked sim + fused partials/signs
    af_naf<<<dim3(1152), b256, 0, stream>>>(x1p, W_adj, b_adj, nafT);
    sim_k<<<dim3(36, 36), b256, 0, stream>>>(nafT, sim, parts, posb);
    // multihead weights FIRST (so Wh fp32 region dies before the mask is written into it)
    gemm_rm<true, false><<<dim3(72, 1, 4), b256, 0, stream>>>(x1p, W_heads, nullptr, Wh, 256, 64,
                                                              (long)256 * 64, (long)NTOT * 64);
    cvt_t<<<dim3(72, 1, 4), b256, 0, stream>>>(Wh, Whbf, 64, (long)NTOT * 64, (long)64 * NTOT);
    dots_k<<<dim3(1152, 4), b256, 0, stream>>>(Wh, a_heads, f1h, f2h, 64);
    // combine partials -> rinv; sign words -> mask (into dead Wh region)
    rowfin<<<dim3(1152), b256, 0, stream>>>(parts, posb, rinv, maskb);
    mh_attn<<<dim3(72, 4, 6), b256, 0, stream>>>(maskb, f1h, f2h, Whbf, acc1, l1);
    mh_fin<<<dim3(NTOT * 256 / 1024), b256, 0, stream>>>(acc1, l1, x1p, x2);
    // zero s partial accumulator (aliases x1p head, now dead)
    zero_k<<<dim3(MU * 256 / 1024), b256, 0, stream>>>(acc2);
    // single GAT
    gemm_rm<false, false><<<dim3(72, 4, 1), b256, 0, stream>>>(x2, W_out, nullptr, Wh2, 256, 256, 0, 0);
    cvt_t<<<dim3(72, 4, 1), b256, 0, stream>>>(Wh2, Wh2bf, 256, 0, 0);
    dots_k<<<dim3(1152, 1), b256, 0, stream>>>(Wh2, a_out, f1s, f2s, 256);
    s_attn<<<dim3(48, 4, 6), b256, 0, stream>>>(maskb, f1s, f2s, Wh2bf, acc2, l2);
    s_fin<<<dim3(MU * 256 / 1024), b256, 0, stream>>>(acc2, l2, x2, x3);
    // feat_mlp rows TC.. -> out[0 : 1536*512]
    gemm_rm<false, true><<<dim3(24, 8, 1), b256, 0, stream>>>(x3, W_lin1, b_lin1, out, 256, 512, 0, 0);
    // bi-softmax outputs
    bi_partial<<<dim3(6, 12, 2), b256, 0, stream>>>(sim, rinv, pmax, psum);
    bi_combine<<<dim3(12), b256, 0, stream>>>(pmax, psum, fmx, fis);
    bi_norm<<<dim3(6, 12, 2), b256, 0, stream>>>(sim, rinv, fmx, fis, out + (long)MU * 512);
}

// Round 17
// 393.582 us; speedup vs baseline: 1.0209x; 1.0209x over previous
//
#include <hip/hip_runtime.h>
#include <hip/hip_bf16.h>
#include <math.h>

// Problem constants (from reference)
constexpr int NTOT = 4608;   // N_NODES
constexpr int TC   = 3072;   // TOTAL_CATS
constexpr int MU   = 1536;   // MAX_UNIFY
constexpr int NH   = 4;      // heads

// ---------------- workspace layout (float offsets) ----------------
constexpr long OFF_ADJ  = 0;                                  // N*N sim region (partially used)
constexpr long OFF_X1   = OFF_ADJ  + (long)NTOT*NTOT;         // N*256 (pre-relu)
constexpr long OFF_NAF  = OFF_X1   + (long)NTOT*256;          // naf_T [64][NTOT]
constexpr long OFF_PART = OFF_NAF  + (long)NTOT*64;           // (unused)
constexpr long OFF_RINV = OFF_PART + 72*64;                   // N
constexpr long OFF_WH   = OFF_RINV + NTOT;                    // 4*N*64  (later: mask bitfield)
constexpr long OFF_F1H  = OFF_WH   + (long)4*NTOT*64;         // 4*N
constexpr long OFF_F2H  = OFF_F1H  + (long)4*NTOT;
constexpr long OFF_MXH  = OFF_F2H  + (long)4*NTOT;            // (unused)
constexpr long OFF_CIH  = OFF_MXH  + (long)4*NTOT;            // (unused)
constexpr long OFF_X2   = OFF_CIH  + (long)4*NTOT;            // N*256
constexpr long OFF_WH2  = OFF_X2   + (long)NTOT*256;          // N*256 (acc1 before Wh2 exists)
constexpr long OFF_F1S  = OFF_WH2  + (long)NTOT*256;          // N
constexpr long OFF_F2S  = OFF_F1S  + NTOT;
constexpr long OFF_MXS  = OFF_F2S  + NTOT;                    // (unused)
constexpr long OFF_CIS  = OFF_MXS  + NTOT;                    // (unused)
constexpr long OFF_X3   = OFF_CIS  + NTOT;                    // 1536*256
constexpr long OFF_PMAX = OFF_X3   + (long)MU*256;            // 2*12*1536
constexpr long OFF_PSUM = OFF_PMAX + (long)2*12*MU;
constexpr long OFF_FMAX = OFF_PSUM + (long)2*12*MU;           // 2*1536
constexpr long OFF_FIS  = OFF_FMAX + (long)2*MU;
constexpr long OFF_L1   = OFF_FIS  + (long)2*MU;              // 4*N unnormalized row sums (mh)
constexpr long OFF_L2   = OFF_L1   + (long)4*NTOT;            // MU row sums (s)
// sim region: values stored ONLY for rows<TC, cols>=TC. Rows>=TC carved as scratch:
constexpr long OFF_PARTS = OFF_ADJ + (long)TC*NTOT;           // double[NTOT][72] row-sum partials
constexpr long OFF_POSB  = OFF_PARTS + 2L*NTOT*72;            // u64[NTOT][72] sign words
// Aliases (lifetime-checked):
//   acc1  = OFF_WH2 region (dead until Wh2 gemm, after mh_fin)
//   Whbf  = OFF_X2 region as bf16 (x2 written only by mh_fin)
//   maskb = OFF_WH region as u64[NTOT][72] (Wh fp32 dead after cvt_t+dots_k)
//   acc2  = OFF_X1 (x1p dead after mh_fin; mh_fin itself zeroes it); Wh2bf = OFF_X1 + MU*256 as bf16

typedef __attribute__((ext_vector_type(8))) short bf16x8;
typedef __attribute__((ext_vector_type(8))) unsigned short ushort8;
typedef __attribute__((ext_vector_type(4))) float floatx4;

__device__ __forceinline__ float lrelu(float x) { return (x >= 0.f) ? x : 0.2f * x; }
__device__ __forceinline__ float elu(float x)   { return (x > 0.f) ? x : expm1f(x); }
__device__ __forceinline__ unsigned short f2bf(float f) {
    unsigned u = __float_as_uint(f);
    u += 0x7FFFu + ((u >> 16) & 1u);           // round-to-nearest-even
    return (unsigned short)(u >> 16);
}

// ---------------- zero-fill two regions (float4 units) ----------------
__global__ __launch_bounds__(256) void zero2_k(
    float* __restrict__ a, long na4, float* __restrict__ b, long nb4)
{
    long i = (long)blockIdx.x * 256 + threadIdx.x;
    float4 z = make_float4(0.f, 0.f, 0.f, 0.f);
    if (i < na4) *(float4*)(a + i * 4) = z;
    else {
        long j = i - na4;
        if (j < nb4) *(float4*)(b + j * 4) = z;
    }
}

// ---------------- convert + transpose: in [Z][NTOT][D] fp32 -> out [Z][D][NTOT] bf16 ----------------
__global__ __launch_bounds__(256) void cvt_t(
    const float* __restrict__ in, unsigned short* __restrict__ out,
    int D, long inZ, long outZ)
{
    __shared__ float t[64][65];
    int n0 = blockIdx.x * 64, d0 = blockIdx.y * 64;
    const float* inz = in + (long)blockIdx.z * inZ;
    unsigned short* outz = out + (long)blockIdx.z * outZ;
    int tid = threadIdx.x;
    int r4 = tid >> 6, k = tid & 63;
    #pragma unroll
    for (int l = 0; l < 16; ++l) {
        int row = l * 4 + r4;
        t[row][k] = inz[(long)(n0 + row) * D + d0 + k];
    }
    __syncthreads();
    #pragma unroll
    for (int l = 0; l < 16; ++l) {
        int drow = l * 4 + r4;
        outz[(long)(d0 + drow) * NTOT + n0 + k] = f2bf(t[k][drow]);
    }
}

// ---------------- generic tiled fp32 GEMM: C = A(NxK) @ B(KxM) [+bias] ----------------
template<bool RELU_A, bool BIAS>
__global__ __launch_bounds__(256) void gemm_rm(
    const float* __restrict__ A, const float* __restrict__ B,
    const float* __restrict__ bias, float* __restrict__ C,
    int K, int M, long strideBz, long strideCz)
{
    __shared__ float As[16][68];
    __shared__ float Bs[16][68];
    const float* Bz = B + (long)blockIdx.z * strideBz;
    float* Cz = C + (long)blockIdx.z * strideCz;
    int tid = threadIdx.x;
    int r0 = blockIdx.x * 64;
    int c0 = blockIdx.y * 64;
    int ty = tid >> 4, tx = tid & 15;
    int srow = tid >> 2, skg = tid & 3;     // As staging role
    float acc[4][4] = {};
    for (int k0 = 0; k0 < K; k0 += 16) {
        {
            float4 v = *(const float4*)&A[(long)(r0 + srow) * K + k0 + skg * 4];
            if (RELU_A) {
                v.x = fmaxf(v.x, 0.f); v.y = fmaxf(v.y, 0.f);
                v.z = fmaxf(v.z, 0.f); v.w = fmaxf(v.w, 0.f);
            }
            As[skg * 4 + 0][srow] = v.x;
            As[skg * 4 + 1][srow] = v.y;
            As[skg * 4 + 2][srow] = v.z;
            As[skg * 4 + 3][srow] = v.w;
        }
        #pragma unroll
        for (int l = 0; l < 4; ++l) {
            int idx = l * 256 + tid;
            int kk = idx >> 6, col = idx & 63;
            Bs[kk][col] = Bz[(long)(k0 + kk) * M + c0 + col];
        }
        __syncthreads();
        #pragma unroll
        for (int kk = 0; kk < 16; ++kk) {
            float4 av = *(const float4*)&As[kk][ty * 4];
            float4 bv = *(const float4*)&Bs[kk][tx * 4];
            float a[4] = { av.x, av.y, av.z, av.w };
            float b[4] = { bv.x, bv.y, bv.z, bv.w };
            #pragma unroll
            for (int i = 0; i < 4; ++i)
                #pragma unroll
                for (int j = 0; j < 4; ++j) acc[i][j] += a[i] * b[j];
        }
        __syncthreads();
    }
    #pragma unroll
    for (int i = 0; i < 4; ++i) {
        int r = r0 + ty * 4 + i;
        #pragma unroll
        for (int j = 0; j < 4; ++j) {
            int c = c0 + tx * 4 + j;
            float v = acc[i][j];
            if (BIAS) v += bias[c];
            Cz[(long)r * M + c] = v;
        }
    }
}

// ---------------- af = x1 @ W_adj + b_adj; naf_T[k][n] = af/||af|| (transposed) ----------------
__global__ __launch_bounds__(256) void af_naf(
    const float* __restrict__ x1, const float* __restrict__ W_adj,
    const float* __restrict__ b_adj, float* __restrict__ nafT)
{
    __shared__ float rowbuf[4][256];
    int tid = threadIdx.x, w = tid >> 6, lane = tid & 63;
    int n = blockIdx.x * 4 + w;
    #pragma unroll
    for (int l = 0; l < 4; ++l) rowbuf[w][l * 64 + lane] = x1[(long)n * 256 + l * 64 + lane];
    __syncthreads();
    float acc = b_adj[lane];
    for (int k = 0; k < 256; ++k) acc += rowbuf[w][k] * W_adj[k * 64 + lane];
    float sq = acc * acc;
    #pragma unroll
    for (int off = 32; off >= 1; off >>= 1) sq += __shfl_xor(sq, off);
    float nrm = fmaxf(sqrtf(sq), 1e-12f);
    nafT[(long)lane * NTOT + n] = acc / nrm;
}

// ---------------- sim 64x64 tile (full grid) + fused fp64 row-partials + sign words ----------------
// Staging: lane = row (coalesced global reads, conflict-free LDS writes). [R15-proven: 0 conflicts]
__global__ __launch_bounds__(256) void sim_k(
    const float* __restrict__ nafT, float* __restrict__ sim,
    double* __restrict__ parts, unsigned long long* __restrict__ posb)
{
    __shared__ float As[64][68];   // [k][n-tile]
    __shared__ float Bs[64][68];   // [k][m-tile]
    __shared__ unsigned char sgn[64][16];
    int tid = threadIdx.x;
    int n0 = blockIdx.x * 64, m0 = blockIdx.y * 64;
    int row = tid & 63, kb = tid >> 6;     // lane = row: coalesced + conflict-free
    #pragma unroll
    for (int l = 0; l < 16; ++l) {
        int k = l * 4 + kb;
        As[k][row] = nafT[(long)k * NTOT + n0 + row];
        Bs[k][row] = nafT[(long)k * NTOT + m0 + row];
    }
    __syncthreads();
    int ty = tid >> 4, tx = tid & 15;
    float acc[4][4] = {};
    for (int kk = 0; kk < 64; ++kk) {
        float4 av = *(const float4*)&As[kk][ty * 4];   // broadcast -> free
        float4 bv = *(const float4*)&Bs[kk][tx * 4];   // 2 lanes/bank -> free
        float a[4] = { av.x, av.y, av.z, av.w };
        float b[4] = { bv.x, bv.y, bv.z, bv.w };
        #pragma unroll
        for (int i = 0; i < 4; ++i)
            #pragma unroll
            for (int j = 0; j < 4; ++j) acc[i][j] += a[i] * b[j];
    }
    // values only for bi-softmax slice
    if (m0 >= TC && n0 < TC) {
        #pragma unroll
        for (int i = 0; i < 4; ++i) {
            long r = n0 + ty * 4 + i;
            float4 o = make_float4(acc[i][0], acc[i][1], acc[i][2], acc[i][3]);
            *(float4*)(sim + r * NTOT + m0 + tx * 4) = o;
        }
    }
    // fused per-row fp64 partials + sign nibbles
    int mt = m0 >> 6;
    #pragma unroll
    for (int i = 0; i < 4; ++i) {
        double t = ((double)acc[i][0] + (double)acc[i][1]) + ((double)acc[i][2] + (double)acc[i][3]);
        #pragma unroll
        for (int off = 1; off < 16; off <<= 1) t += __shfl_xor(t, off);
        unsigned nib = (unsigned)(acc[i][0] > 0.f) | ((unsigned)(acc[i][1] > 0.f) << 1)
                     | ((unsigned)(acc[i][2] > 0.f) << 2) | ((unsigned)(acc[i][3] > 0.f) << 3);
        sgn[ty * 4 + i][tx] = (unsigned char)nib;
        if (tx == 0) parts[(long)(n0 + ty * 4 + i) * 72 + mt] = t;
    }
    __syncthreads();
    if (tid < 64) {
        unsigned long long w = 0;
        #pragma unroll
        for (int t = 0; t < 16; ++t)
            w |= (unsigned long long)sgn[tid][t] << (4 * t);
        posb[(long)(n0 + tid) * 72 + mt] = w;
    }
}

// ---------------- rowfin: combine 72 partials -> rinv; sign words -> mask words ----------------
__global__ __launch_bounds__(256) void rowfin(
    const double* __restrict__ parts, const unsigned long long* __restrict__ posb,
    float* __restrict__ rinv, unsigned long long* __restrict__ maskb)
{
    int tid = threadIdx.x, w = tid >> 6, lane = tid & 63;
    int n = blockIdx.x * 4 + w;
    double s = parts[(long)n * 72 + lane];
    if (lane < 8) s += parts[(long)n * 72 + 64 + lane];
    #pragma unroll
    for (int off = 32; off >= 1; off >>= 1) s += __shfl_xor(s, off);
    float rs = (float)s;
    float r = 1.0f / rs;
    if (isinf(r)) r = 0.f;
    if (lane == 0) rinv[n] = r;
    unsigned long long pw = posb[(long)n * 72 + lane];
    unsigned long long mw = (r < 0.f) ? ~pw : pw;
    if (r == 0.f) mw = 0ull;
    maskb[(long)n * 72 + lane] = mw;
    if (lane < 8) {
        pw = posb[(long)n * 72 + 64 + lane];
        mw = (r < 0.f) ? ~pw : pw;
        if (r == 0.f) mw = 0ull;
        maskb[(long)n * 72 + 64 + lane] = mw;
    }
}

// ---------------- f1/f2 dots ----------------
__global__ __launch_bounds__(256) void dots_k(
    const float* __restrict__ Wh, const float* __restrict__ a,
    float* __restrict__ f1, float* __restrict__ f2, int D)
{
    int tid = threadIdx.x, w = tid >> 6, lane = tid & 63;
    int n = blockIdx.x * 4 + w;
    int h = blockIdx.y;
    const float* row = Wh + ((long)h * NTOT + n) * D;
    const float* a1 = a + (long)h * 2 * D;
    const float* a2 = a1 + D;
    float p1 = 0.f, p2 = 0.f;
    for (int d = lane; d < D; d += 64) {
        float v = row[d];
        p1 += v * a1[d];
        p2 += v * a2[d];
    }
    #pragma unroll
    for (int off = 32; off >= 1; off >>= 1) { p1 += __shfl_xor(p1, off); p2 += __shfl_xor(p2, off); }
    if (lane == 0) { f1[(long)h * NTOT + n] = p1; f2[(long)h * NTOT + n] = p2; }
}

// ---------------- multihead att @ Wh via bf16 MFMA, mask-bit P, in-register A-frags ----------------
__global__ __launch_bounds__(256) void mh_attn(
    const unsigned long long* __restrict__ maskb,
    const float* __restrict__ f1, const float* __restrict__ f2,
    const unsigned short* __restrict__ Whbf, float* __restrict__ accb,
    float* __restrict__ lbuf)
{
    __shared__ unsigned short Ws[2][64][72];   // Wh tile transposed [d][m] bf16
    int tid = threadIdx.x;
    int wave = tid >> 6, lane = tid & 63;
    int n0 = blockIdx.x * 64;
    int h = blockIdx.y, ch = blockIdx.z;
    const float* f2h = f2 + (long)h * NTOT;
    const unsigned short* Wb = Whbf + (long)h * 64 * NTOT;
    int wd = tid >> 2, wc = (tid & 3) * 16;
    int arow = lane & 15, acol8 = (lane >> 4) * 8;
    int n = n0 + 16 * wave + arow;
    float r1 = f1[(long)h * NTOT + n];
    float lsum = 0.f;
    floatx4 acc[4] = {};
    int buf = 0;
    for (int mt = ch * 12; mt < ch * 12 + 12; ++mt) {
        int m0 = mt * 64;
        ushort8 wv0 = *(const ushort8*)&Wb[(long)wd * NTOT + m0 + wc];
        ushort8 wv1 = *(const ushort8*)&Wb[(long)wd * NTOT + m0 + wc + 8];
        unsigned long long mw = maskb[(long)n * 72 + mt];
        bf16x8 afr[2];
        #pragma unroll
        for (int ks = 0; ks < 2; ++ks) {
            int mc = m0 + ks * 32 + acol8;
            float4 fv0 = *(const float4*)(f2h + mc);
            float4 fv1 = *(const float4*)(f2h + mc + 4);
            unsigned bits = (unsigned)(mw >> (ks * 32 + acol8)) & 0xFFu;
            float f[8] = { fv0.x, fv0.y, fv0.z, fv0.w, fv1.x, fv1.y, fv1.z, fv1.w };
            #pragma unroll
            for (int j = 0; j < 8; ++j) {
                float s = r1 + f[j];
                float e = __expf(fmaxf(s, 0.2f * s));
                float p = ((bits >> j) & 1u) ? e : 0.f;
                lsum += p;
                afr[ks][j] = (short)f2bf(p);
            }
        }
        *(ushort8*)&Ws[buf][wd][wc] = wv0;
        *(ushort8*)&Ws[buf][wd][wc + 8] = wv1;
        __syncthreads();
        #pragma unroll
        for (int ks = 0; ks < 2; ++ks) {
            #pragma unroll
            for (int dt = 0; dt < 4; ++dt) {
                bf16x8 bfr = *(bf16x8*)&Ws[buf][16 * dt + arow][ks * 32 + acol8];
                acc[dt] = __builtin_amdgcn_mfma_f32_16x16x32_bf16(afr[ks], bfr, acc[dt], 0, 0, 0);
            }
        }
        buf ^= 1;
    }
    lsum += __shfl_xor(lsum, 16);
    lsum += __shfl_xor(lsum, 32);
    if (lane < 16) atomicAdd(lbuf + (long)h * NTOT + n0 + 16 * wave + lane, lsum);
    int crow = n0 + 16 * wave + (lane >> 4) * 4;
    int ccol = h * 64 + (lane & 15);
    #pragma unroll
    for (int dt = 0; dt < 4; ++dt)
        #pragma unroll
        for (int r = 0; r < 4; ++r)
            atomicAdd(accb + (long)(crow + r) * 256 + ccol + dt * 16, acc[dt][r]);
}

// ---------------- mh epilogue: x2 = elu(acc / l') + relu(x1); also zeroes acc2 region ----------------
__global__ __launch_bounds__(256) void mh_fin(
    const float* __restrict__ accb, const float* __restrict__ lbuf,
    float* __restrict__ x1, float* __restrict__ x2)
{
    long idx = ((long)blockIdx.x * 256 + threadIdx.x) * 4;
    long r = idx >> 8;
    int h = (int)((idx & 255) >> 6);
    float l = lbuf[(long)h * NTOT + r];
    float inv = (l > 0.f) ? 1.0f / l : 0.f;
    float4 a = *(const float4*)(accb + idx);
    float4 xv = *(const float4*)(x1 + idx);
    float4 o;
    o.x = elu(a.x * inv) + fmaxf(xv.x, 0.f);
    o.y = elu(a.y * inv) + fmaxf(xv.y, 0.f);
    o.z = elu(a.z * inv) + fmaxf(xv.z, 0.f);
    o.w = elu(a.w * inv) + fmaxf(xv.w, 0.f);
    *(float4*)(x2 + idx) = o;
    // pre-zero acc2 (aliases head of x1p region, which is dead after this read)
    if (idx < (long)MU * 256)
        *(float4*)(x1 + idx) = make_float4(0.f, 0.f, 0.f, 0.f);
}

// ---------------- single-head att @ Wh2 via bf16 MFMA (rows >= TC), mask-bit P ----------------
// grid (48 row-tiles of 32, 2 col-halves of 128, 12 m-chunks of 6 tiles).
// Each wave: rt=wave&1 (16 rows), (wave>>1) selects 64-col half of this block's 128 cols.
// P redundancy reduced 8x -> 4x vs the old (48,4,6) layout.
__global__ __launch_bounds__(256) void s_attn(
    const unsigned long long* __restrict__ maskb,
    const float* __restrict__ f1, const float* __restrict__ f2,
    const unsigned short* __restrict__ Wh2bf, float* __restrict__ accb,
    float* __restrict__ lbuf)
{
    __shared__ unsigned short Ws[2][128][72];   // 36.9 KB: 128 d-rows x 64 m, dbuf
    int tid = threadIdx.x;
    int wave = tid >> 6, lane = tid & 63;
    int lr0 = blockIdx.x * 32;
    int c0 = blockIdx.y * 128;
    int ch = blockIdx.z;
    int wdl = tid >> 2, wc = (tid & 3) * 16;    // staging role (applied twice for 128 rows)
    int arow = lane & 15, acol8 = (lane >> 4) * 8;
    int rt = wave & 1;
    int dt0 = (wave >> 1) * 4;                   // 4 d-tiles of 16 per wave
    int n = TC + lr0 + 16 * rt + arow;
    float r1 = f1[n];
    float lsum = 0.f;
    floatx4 acc[4] = {};
    int buf = 0;
    for (int mt = ch * 6; mt < ch * 6 + 6; ++mt) {
        int m0 = mt * 64;
        // issue all global loads first (latency hides under P-gen VALU)
        ushort8 wva0 = *(const ushort8*)&Wh2bf[(long)(c0 + wdl) * NTOT + m0 + wc];
        ushort8 wva1 = *(const ushort8*)&Wh2bf[(long)(c0 + wdl) * NTOT + m0 + wc + 8];
        ushort8 wvb0 = *(const ushort8*)&Wh2bf[(long)(c0 + 64 + wdl) * NTOT + m0 + wc];
        ushort8 wvb1 = *(const ushort8*)&Wh2bf[(long)(c0 + 64 + wdl) * NTOT + m0 + wc + 8];
        unsigned long long mw = maskb[(long)n * 72 + mt];
        bf16x8 afr[2];
        #pragma unroll
        for (int ks = 0; ks < 2; ++ks) {
            int mc = m0 + ks * 32 + acol8;
            float4 fv0 = *(const float4*)(f2 + mc);
            float4 fv1 = *(const float4*)(f2 + mc + 4);
            unsigned bits = (unsigned)(mw >> (ks * 32 + acol8)) & 0xFFu;
            float f[8] = { fv0.x, fv0.y, fv0.z, fv0.w, fv1.x, fv1.y, fv1.z, fv1.w };
            #pragma unroll
            for (int j = 0; j < 8; ++j) {
                float s = r1 + f[j];
                float e = __expf(fmaxf(s, 0.2f * s));
                float p = ((bits >> j) & 1u) ? e : 0.f;
                lsum += p;
                afr[ks][j] = (short)f2bf(p);
            }
        }
        *(ushort8*)&Ws[buf][wdl][wc] = wva0;
        *(ushort8*)&Ws[buf][wdl][wc + 8] = wva1;
        *(ushort8*)&Ws[buf][64 + wdl][wc] = wvb0;
        *(ushort8*)&Ws[buf][64 + wdl][wc + 8] = wvb1;
        __syncthreads();
        #pragma unroll
        for (int ks = 0; ks < 2; ++ks) {
            #pragma unroll
            for (int t = 0; t < 4; ++t) {
                bf16x8 bfr = *(bf16x8*)&Ws[buf][(dt0 + t) * 16 + arow][ks * 32 + acol8];
                acc[t] = __builtin_amdgcn_mfma_f32_16x16x32_bf16(afr[ks], bfr, acc[t], 0, 0, 0);
            }
        }
        buf ^= 1;
    }
    // per-row l': contribute once (col-half 0, waves 0,1 only)
    lsum += __shfl_xor(lsum, 16);
    lsum += __shfl_xor(lsum, 32);
    if (blockIdx.y == 0 && wave < 2 && lane < 16)
        atomicAdd(lbuf + lr0 + 16 * wave + lane, lsum);
    int crow = lr0 + 16 * rt + (lane >> 4) * 4;
    #pragma unroll
    for (int t = 0; t < 4; ++t) {
        int ccol = c0 + (dt0 + t) * 16 + (lane & 15);
        #pragma unroll
        for (int r = 0; r < 4; ++r)
            atomicAdd(accb + (long)(crow + r) * 256 + ccol, acc[t][r]);
    }
}

// ---------------- s epilogue: x3 = elu(acc / l' + x2[TC..]) ----------------
__global__ __launch_bounds__(256) void s_fin(
    const float* __restrict__ accb, const float* __restrict__ lbuf,
    const float* __restrict__ x2, float* __restrict__ x3)
{
    long idx = ((long)blockIdx.x * 256 + threadIdx.x) * 4;
    long r = idx >> 8;
    float l = lbuf[r];
    float inv = (l > 0.f) ? 1.0f / l : 0.f;
    float4 a = *(const float4*)(accb + idx);
    float4 xv = *(const float4*)(x2 + (long)TC * 256 + idx);
    float4 o;
    o.x = elu(a.x * inv + xv.x);
    o.y = elu(a.y * inv + xv.y);
    o.z = elu(a.z * inv + xv.z);
    o.w = elu(a.w * inv + xv.w);
    *(float4*)(x3 + idx) = o;
}

// ---------------- bi-softmax phase A ----------------
__global__ __launch_bounds__(256) void bi_partial(
    const float* __restrict__ sim, const float* __restrict__ rinv,
    float* __restrict__ pmax, float* __restrict__ psum)
{
    int c = blockIdx.x * 256 + threadIdx.x;
    int ch = blockIdx.y;
    int ds = blockIdx.z;
    float m = -3.0e38f, s = 0.f;
    int rbase = ds * MU + ch * 128;
    for (int r = 0; r < 128; ++r) {
        float a = sim[(long)(rbase + r) * NTOT + TC + c] * rinv[rbase + r];
        float v = a * 20.0f;
        if (v <= m) s += expf(v - m);
        else { s = s * expf(m - v) + 1.f; m = v; }
    }
    pmax[((long)ds * 12 + ch) * MU + c] = m;
    psum[((long)ds * 12 + ch) * MU + c] = s;
}

// ---------------- bi-softmax phase B ----------------
__global__ __launch_bounds__(256) void bi_combine(
    const float* __restrict__ pmax, const float* __restrict__ psum,
    float* __restrict__ fmax, float* __restrict__ fis)
{
    int b = blockIdx.x;
    int ds = b / 6, ct = b % 6;
    int c = ct * 256 + threadIdx.x;
    float m = -3.0e38f;
    for (int ch = 0; ch < 12; ++ch) m = fmaxf(m, pmax[((long)ds * 12 + ch) * MU + c]);
    float s = 0.f;
    for (int ch = 0; ch < 12; ++ch)
        s += psum[((long)ds * 12 + ch) * MU + c] * expf(pmax[((long)ds * 12 + ch) * MU + c] - m);
    fmax[ds * MU + c] = m;
    fis[ds * MU + c] = 1.0f / s;
}

// ---------------- bi-softmax phase C ----------------
__global__ __launch_bounds__(256) void bi_norm(
    const float* __restrict__ sim, const float* __restrict__ rinv,
    const float* __restrict__ fmax, const float* __restrict__ fis,
    float* __restrict__ outbg)
{
    int c = blockIdx.x * 256 + threadIdx.x;
    int ch = blockIdx.y;
    int ds = blockIdx.z;
    float m = fmax[ds * MU + c], inv = fis[ds * MU + c];
    long obase = (long)ds * MU * MU;
    int rbase = ch * 128;
    for (int r = 0; r < 128; ++r) {
        int row = ds * MU + rbase + r;
        float a = sim[(long)row * NTOT + TC + c] * rinv[row];
        float v = a * 20.0f;
        outbg[obase + (long)(rbase + r) * MU + c] = expf(v - m) * inv;
    }
}

// ---------------- launch ----------------
extern "C" void kernel_launch(void* const* d_in, const int* in_sizes, int n_in,
                              void* d_out, int out_size, void* d_ws, size_t ws_size,
                              hipStream_t stream)
{
    const float* x        = (const float*)d_in[0];
    const float* W_before = (const float*)d_in[1];
    const float* b_before = (const float*)d_in[2];
    const float* W_adj    = (const float*)d_in[3];
    const float* b_adj    = (const float*)d_in[4];
    const float* W_heads  = (const float*)d_in[5];
    const float* a_heads  = (const float*)d_in[6];
    const float* W_out    = (const float*)d_in[7];
    const float* a_out    = (const float*)d_in[8];
    const float* W_lin1   = (const float*)d_in[9];
    const float* b_lin1   = (const float*)d_in[10];
    float* out = (float*)d_out;
    float* ws  = (float*)d_ws;

    float* sim  = ws + OFF_ADJ;
    float* x1p  = ws + OFF_X1;
    float* nafT = ws + OFF_NAF;
    float* rinv = ws + OFF_RINV;
    float* Wh   = ws + OFF_WH;
    float* f1h  = ws + OFF_F1H;
    float* f2h  = ws + OFF_F2H;
    float* x2   = ws + OFF_X2;
    float* Wh2  = ws + OFF_WH2;
    float* f1s  = ws + OFF_F1S;
    float* f2s  = ws + OFF_F2S;
    float* x3   = ws + OFF_X3;
    float* pmax = ws + OFF_PMAX;
    float* psum = ws + OFF_PSUM;
    float* fmx  = ws + OFF_FMAX;
    float* fis  = ws + OFF_FIS;
    float* l1   = ws + OFF_L1;
    float* l2   = ws + OFF_L2;
    float* acc1 = ws + OFF_WH2;                               // alias (see layout notes)
    float* acc2 = ws + OFF_X1;                                // alias (zeroed by mh_fin)
    unsigned short* Whbf  = (unsigned short*)(ws + OFF_X2);   // alias: x2 region before mh_fin
    unsigned short* Wh2bf = (unsigned short*)(ws + OFF_X1 + (long)MU * 256);  // alias
    unsigned long long* maskb = (unsigned long long*)(ws + OFF_WH);  // alias: Wh fp32 dead after dots_k
    double* parts = (double*)(ws + OFF_PARTS);                // in dead sim rows >= TC
    unsigned long long* posb = (unsigned long long*)(ws + OFF_POSB);

    dim3 b256(256);

    // zero mh partial accumulator + l1/l2 row-sum buffers in one launch
    zero2_k<<<dim3(1172), b256, 0, stream>>>(acc1, (long)NTOT * 64, l1, 5120);
    // x1_pre = x @ W_before + b
    gemm_rm<false, true><<<dim3(72, 4, 1), b256, 0, stream>>>(x, W_before, b_before, x1p, 512, 256, 0, 0);
    // adjacency features: transposed naf, full-grid sim + fused partials/signs
    af_naf<<<dim3(1152), b256, 0, stream>>>(x1p, W_adj, b_adj, nafT);
    sim_k<<<dim3(72, 72), b256, 0, stream>>>(nafT, sim, parts, posb);
    // multihead weights FIRST (so Wh fp32 region dies before the mask is written into it)
    gemm_rm<true, false><<<dim3(72, 1, 4), b256, 0, stream>>>(x1p, W_heads, nullptr, Wh, 256, 64,
                                                              (long)256 * 64, (long)NTOT * 64);
    cvt_t<<<dim3(72, 1, 4), b256, 0, stream>>>(Wh, Whbf, 64, (long)NTOT * 64, (long)64 * NTOT);
    dots_k<<<dim3(1152, 4), b256, 0, stream>>>(Wh, a_heads, f1h, f2h, 64);
    // combine partials -> rinv; sign words -> mask (into dead Wh region)
    rowfin<<<dim3(1152), b256, 0, stream>>>(parts, posb, rinv, maskb);
    mh_attn<<<dim3(72, 4, 6), b256, 0, stream>>>(maskb, f1h, f2h, Whbf, acc1, l1);
    mh_fin<<<dim3(NTOT * 256 / 1024), b256, 0, stream>>>(acc1, l1, x1p, x2);
    // single GAT (acc2 already zeroed by mh_fin)
    gemm_rm<false, false><<<dim3(72, 4, 1), b256, 0, stream>>>(x2, W_out, nullptr, Wh2, 256, 256, 0, 0);
    cvt_t<<<dim3(72, 4, 1), b256, 0, stream>>>(Wh2, Wh2bf, 256, 0, 0);
    dots_k<<<dim3(1152, 1), b256, 0, stream>>>(Wh2, a_out, f1s, f2s, 256);
    s_attn<<<dim3(48, 2, 12), b256, 0, stream>>>(maskb, f1s, f2s, Wh2bf, acc2, l2);
    s_fin<<<dim3(MU * 256 / 1024), b256, 0, stream>>>(acc2, l2, x2, x3);
    // feat_mlp rows TC.. -> out[0 : 1536*512]
    gemm_rm<false, true><<<dim3(24, 8, 1), b256, 0, stream>>>(x3, W_lin1, b_lin1, out, 256, 512, 0, 0);
    // bi-softmax outputs
    bi_partial<<<dim3(6, 12, 2), b256, 0, stream>>>(sim, rinv, pmax, psum);
    bi_combine<<<dim3(12), b256, 0, stream>>>(pmax, psum, fmx, fis);
    bi_norm<<<dim3(6, 12, 2), b256, 0, stream>>>(sim, rinv, fmx, fis, out + (long)MU * 512);
}